// Round 1
// baseline (149.322 us; speedup 1.0000x reference)
//
#include <hip/hip_runtime.h>
#include <hip/hip_bf16.h>
#include <hip/hip_fp16.h>

#define N_NODES 50000
#define N_EDGES 800000
#define IN_DIM 128
#define OUT_DIM 64
#define NEG_SLOPE 0.01f
#define NEG_INF (-3.0e38f)

#define N_STRIPS (N_NODES / 16)       // 3125 16-node MFMA strips
#define Z_BLOCKS ((N_STRIPS + 3) / 4) // 782 (4 waves/block, 1 strip/wave)
#define E_I4 (N_EDGES / 4)            // 200000 int4 edge groups

// bucket sort: 128 nodes/bucket; block-local count -> reserve -> place
#define NB ((N_NODES + 127) / 128)    // 391 buckets
#define CAP_B 3072                     // slab capacity (mean occupancy 2046)
#define CNT_STRIDE 16                  // 64B line per bucket cursor
#define EB 100                         // edge blocks
#define CHUNK_I4 (E_I4 / EB)           // 2000 int4 = 8000 edges per block

typedef __bf16 bf16x8 __attribute__((ext_vector_type(8)));
typedef float f32x4 __attribute__((ext_vector_type(4)));

__device__ __forceinline__ unsigned short f2bf_us(float f) {
  __hip_bfloat16 h = __float2bfloat16(f);  // RNE
  return *reinterpret_cast<unsigned short*>(&h);
}
__device__ __forceinline__ bf16x8 pack_bf16(float4 lo, float4 hi) {
  union { bf16x8 v; unsigned short u[8]; } r;
  r.u[0] = f2bf_us(lo.x); r.u[1] = f2bf_us(lo.y);
  r.u[2] = f2bf_us(lo.z); r.u[3] = f2bf_us(lo.w);
  r.u[4] = f2bf_us(hi.x); r.u[5] = f2bf_us(hi.y);
  r.u[6] = f2bf_us(hi.z); r.u[7] = f2bf_us(hi.w);
  return r.v;
}
__device__ __forceinline__ float bflo(unsigned u) {
  return __uint_as_float(u << 16);
}
__device__ __forceinline__ float bfhi(unsigned u) {
  return __uint_as_float(u & 0xffff0000u);
}

// ---------------------------------------------------------------------------
// Stage 1 (fused). Blocks [0, Z_BLOCKS): MFMA z-GEMM (R7 structure).
// Blocks [Z_BLOCKS,...): bucket pass (no per-edge global atomics:
// LDS count -> one reserve atomic per (block,bucket) -> place).
// ---------------------------------------------------------------------------
__global__ __launch_bounds__(256) void gat_z_bucket(
    const float* __restrict__ feat, const float* __restrict__ fcw,
    const float* __restrict__ attnw, __hip_bfloat16* __restrict__ z,
    float* __restrict__ asrc, float* __restrict__ adst,
    const int* __restrict__ src, const int* __restrict__ dst,
    int* __restrict__ cnt, unsigned* __restrict__ pairs) {
  if (blockIdx.x >= Z_BLOCKS) {
    __shared__ int hist[NB];
    __shared__ int curs[NB];
    const int tid = threadIdx.x;
    const int i0 = (blockIdx.x - Z_BLOCKS) * CHUNK_I4;
    for (int i = tid; i < NB; i += 256) hist[i] = 0;
    __syncthreads();
    for (int t = i0 + tid; t < i0 + CHUNK_I4; t += 256) {
      int4 d = ((const int4*)dst)[t];
      atomicAdd(&hist[d.x >> 7], 1);
      atomicAdd(&hist[d.y >> 7], 1);
      atomicAdd(&hist[d.z >> 7], 1);
      atomicAdd(&hist[d.w >> 7], 1);
    }
    __syncthreads();
    for (int i = tid; i < NB; i += 256) {
      int h = hist[i];
      curs[i] = h ? atomicAdd(cnt + i * CNT_STRIDE, h) : 0;
    }
    __syncthreads();
    for (int t = i0 + tid; t < i0 + CHUNK_I4; t += 256) {
      int4 s = ((const int4*)src)[t];
      int4 d = ((const int4*)dst)[t];
#define BKT_PUT(dd, ss)                                                    \
  {                                                                        \
    int b = (dd) >> 7;                                                     \
    int r = atomicAdd(&curs[b], 1);                                        \
    if (r < CAP_B)                                                         \
      pairs[(size_t)b * CAP_B + r] =                                       \
          ((unsigned)((dd) & 127) << 16) | (unsigned)(ss);                 \
  }
      BKT_PUT(d.x, s.x)
      BKT_PUT(d.y, s.y)
      BKT_PUT(d.z, s.z)
      BKT_PUT(d.w, s.w)
#undef BKT_PUT
    }
    return;
  }

  const int lane = threadIdx.x & 63;
  const int m = lane & 15;
  const int quad = lane >> 4;
  const int wv = blockIdx.x * 4 + (threadIdx.x >> 6);
  if (wv >= N_STRIPS) return;
  const int n0 = wv * 16;

  bf16x8 bfrag[4][4];
#pragma unroll
  for (int t = 0; t < 4; ++t) {
    const float* wr = fcw + (size_t)(m + 16 * t) * IN_DIM + quad * 8;
#pragma unroll
    for (int c = 0; c < 4; ++c) {
      float4 lo = *(const float4*)(wr + c * 32);
      float4 hi = *(const float4*)(wr + c * 32 + 4);
      bfrag[t][c] = pack_bf16(lo, hi);
    }
  }

  f32x4 acc[4] = {{0.f, 0.f, 0.f, 0.f}, {0.f, 0.f, 0.f, 0.f},
                  {0.f, 0.f, 0.f, 0.f}, {0.f, 0.f, 0.f, 0.f}};
  const float* ar = feat + (size_t)(n0 + m) * IN_DIM + quad * 8;
#pragma unroll
  for (int c = 0; c < 4; ++c) {
    float4 lo = *(const float4*)(ar + c * 32);
    float4 hi = *(const float4*)(ar + c * 32 + 4);
    const bf16x8 af = pack_bf16(lo, hi);
#pragma unroll
    for (int t = 0; t < 4; ++t)
      acc[t] = __builtin_amdgcn_mfma_f32_16x16x32_bf16(af, bfrag[t][c],
                                                       acc[t], 0, 0, 0);
  }

#pragma unroll
  for (int t = 0; t < 4; ++t)
#pragma unroll
    for (int r = 0; r < 4; ++r)
      z[(size_t)(n0 + quad * 4 + r) * OUT_DIM + m + 16 * t] =
          __float2bfloat16(acc[t][r]);

  float aws[4], awd[4];
#pragma unroll
  for (int t = 0; t < 4; ++t) {
    aws[t] = attnw[m + 16 * t];
    awd[t] = attnw[OUT_DIM + m + 16 * t];
  }
  float ps[4], pd[4];
#pragma unroll
  for (int r = 0; r < 4; ++r) {
    float s = 0.f, d = 0.f;
#pragma unroll
    for (int t = 0; t < 4; ++t) {
      s = fmaf(acc[t][r], aws[t], s);
      d = fmaf(acc[t][r], awd[t], d);
    }
    ps[r] = s;
    pd[r] = d;
  }
#pragma unroll
  for (int off = 1; off < 16; off <<= 1) {
#pragma unroll
    for (int r = 0; r < 4; ++r) {
      ps[r] += __shfl_xor(ps[r], off, 64);
      pd[r] += __shfl_xor(pd[r], off, 64);
    }
  }
  if (m == 0) {
#pragma unroll
    for (int r = 0; r < 4; ++r) {
      asrc[n0 + quad * 4 + r] = ps[r];
      adst[n0 + quad * 4 + r] = pd[r];
    }
  }
}

// ---------------------------------------------------------------------------
// Fused bucket-local CSR + aggregation. Two blocks per bucket (half = 64
// nodes each, for load balance: 782 blocks x 512 thr ~ 3 blocks/CU).
// Block: classify slab -> LDS hist(64) -> 64-lane shfl scan -> place into
// LDS lsrc -> 8 waves aggregate 8 nodes each (online softmax, identical
// per-node body to the previous gat_agg, edge list now read from LDS).
// No global offsets / ssorted arrays, no separate CSR kernel.
// ---------------------------------------------------------------------------
__global__ __launch_bounds__(512) void gat_csr_agg(
    const unsigned* __restrict__ pairs, const int* __restrict__ cnt,
    const __hip_bfloat16* __restrict__ zb, const float* __restrict__ asrc,
    const float* __restrict__ adst, float* __restrict__ out) {
  __shared__ int hist[64];
  __shared__ int noff[65];
  __shared__ int cur[64];
  __shared__ int lsrc[CAP_B];
  const int tid = threadIdx.x;
  const int b = blockIdx.x >> 1;
  const int half = blockIdx.x & 1;
  const int c = min(cnt[b * CNT_STRIDE], CAP_B);
  const unsigned* __restrict__ bp = pairs + (size_t)b * CAP_B;

  if (tid < 64) hist[tid] = 0;
  __syncthreads();
  for (int i = tid; i < c; i += 512) {
    const int ln = (int)(bp[i] >> 16);
    if ((ln >> 6) == half) atomicAdd(&hist[ln & 63], 1);
  }
  __syncthreads();
  if (tid < 64) {
    const int h = hist[tid];
    int s = h;
#pragma unroll
    for (int off = 1; off < 64; off <<= 1) {
      const int u = __shfl_up(s, off, 64);
      if (tid >= off) s += u;
    }
    noff[tid] = s - h;
    cur[tid] = s - h;
    if (tid == 63) noff[64] = s;
  }
  __syncthreads();
  for (int i = tid; i < c; i += 512) {
    const unsigned p = bp[i];
    const int ln = (int)(p >> 16);
    if ((ln >> 6) == half) {
      const int r = atomicAdd(&cur[ln & 63], 1);
      lsrc[r] = (int)(p & 0xFFFFu);
    }
  }
  __syncthreads();

  const int lane = tid & 63;
  const int wv = tid >> 6;   // 0..7
  const int j = lane & 7;    // column quad: cols 8j..8j+7
  const int eg = lane >> 3;  // edge subgroup 0..7
  const uint4* __restrict__ zp4 = (const uint4*)zb;  // 8 uint4 per 64-col row

#pragma unroll 1
  for (int k = 0; k < 8; ++k) {
    const int ln = wv * 8 + k;
    const int node = b * 128 + half * 64 + ln;
    if (node >= N_NODES) break;
    const int o0 = noff[ln];
    const int o1 = noff[ln + 1];
    float4* __restrict__ orow = (float4*)(out + (size_t)node * OUT_DIM);
    if (o0 == o1) {  // no incoming edges: elu(0/1) = 0
      if (eg == 0) {
        const float4 zv = {0.f, 0.f, 0.f, 0.f};
        orow[2 * j] = zv;
        orow[2 * j + 1] = zv;
      }
      continue;
    }
    const float ad = adst[node];

    float m = NEG_INF, dsum = 0.f;
    float acca[8] = {0.f, 0.f, 0.f, 0.f, 0.f, 0.f, 0.f, 0.f};
    float accb[8] = {0.f, 0.f, 0.f, 0.f, 0.f, 0.f, 0.f, 0.f};

    for (int base = o0; base < o1; base += 64) {
      const int cnt2 = min(64, o1 - base);
      int s = 0;
      float ev = NEG_INF;
      if (lane < cnt2) {
        s = lsrc[base + lane];
        const float v = asrc[s] + ad;
        ev = v > 0.f ? v : NEG_SLOPE * v;
      }
      float cm = ev;
#pragma unroll
      for (int off = 32; off; off >>= 1)
        cm = fmaxf(cm, __shfl_xor(cm, off, 64));
      const float nm = fmaxf(m, cm);
      const float scale = __expf(m - nm);  // first chunk: exp(-inf) = 0
      dsum *= scale;
#pragma unroll
      for (int cc = 0; cc < 8; ++cc) {
        acca[cc] *= scale;
        accb[cc] *= scale;
      }
      m = nm;

      const float w = (lane < cnt2) ? __expf(ev - m) : 0.f;  // 0 beyond cnt
      dsum += w;
      // pack s (16b) | f16(w) (16b); s=0,w=0 for idle lanes -> harmless
      const unsigned pk =
          (unsigned)s |
          ((unsigned)__half_as_ushort(__float2half(w)) << 16);

      const int ngr = (cnt2 + 7) >> 3;
      for (int g = 0; g < ngr; g += 2) {
        const unsigned pa = __shfl(pk, 8 * g + eg, 64);
        const int sa = (int)(pa & 0xFFFFu);
        const float wa =
            __half2float(__ushort_as_half((unsigned short)(pa >> 16)));
        const uint4 ua = zp4[(size_t)sa * 8 + j];
        if (g + 1 < ngr) {
          const unsigned pb = __shfl(pk, 8 * (g + 1) + eg, 64);
          const int sb = (int)(pb & 0xFFFFu);
          const float wb =
              __half2float(__ushort_as_half((unsigned short)(pb >> 16)));
          const uint4 ub = zp4[(size_t)sb * 8 + j];
          accb[0] = fmaf(wb, bflo(ub.x), accb[0]);
          accb[1] = fmaf(wb, bfhi(ub.x), accb[1]);
          accb[2] = fmaf(wb, bflo(ub.y), accb[2]);
          accb[3] = fmaf(wb, bfhi(ub.y), accb[3]);
          accb[4] = fmaf(wb, bflo(ub.z), accb[4]);
          accb[5] = fmaf(wb, bfhi(ub.z), accb[5]);
          accb[6] = fmaf(wb, bflo(ub.w), accb[6]);
          accb[7] = fmaf(wb, bfhi(ub.w), accb[7]);
        }
        acca[0] = fmaf(wa, bflo(ua.x), acca[0]);
        acca[1] = fmaf(wa, bfhi(ua.x), acca[1]);
        acca[2] = fmaf(wa, bflo(ua.y), acca[2]);
        acca[3] = fmaf(wa, bfhi(ua.y), acca[3]);
        acca[4] = fmaf(wa, bflo(ua.z), acca[4]);
        acca[5] = fmaf(wa, bfhi(ua.z), acca[5]);
        acca[6] = fmaf(wa, bflo(ua.w), acca[6]);
        acca[7] = fmaf(wa, bfhi(ua.w), acca[7]);
      }
    }

    float acc[8];
#pragma unroll
    for (int cc = 0; cc < 8; ++cc) acc[cc] = acca[cc] + accb[cc];
#pragma unroll
    for (int off = 8; off < 64; off <<= 1)
#pragma unroll
      for (int cc = 0; cc < 8; ++cc) acc[cc] += __shfl_xor(acc[cc], off, 64);
#pragma unroll
    for (int off = 32; off; off >>= 1) dsum += __shfl_xor(dsum, off, 64);

    if (eg == 0) {
      const float inv = 1.f / (dsum > 0.f ? dsum : 1.f);
      float4 r0, r1;
      float h;
      h = acc[0] * inv; r0.x = h > 0.f ? h : expm1f(h);
      h = acc[1] * inv; r0.y = h > 0.f ? h : expm1f(h);
      h = acc[2] * inv; r0.z = h > 0.f ? h : expm1f(h);
      h = acc[3] * inv; r0.w = h > 0.f ? h : expm1f(h);
      h = acc[4] * inv; r1.x = h > 0.f ? h : expm1f(h);
      h = acc[5] * inv; r1.y = h > 0.f ? h : expm1f(h);
      h = acc[6] * inv; r1.z = h > 0.f ? h : expm1f(h);
      h = acc[7] * inv; r1.w = h > 0.f ? h : expm1f(h);
      orow[2 * j] = r0;
      orow[2 * j + 1] = r1;
    }
  }
}

// ---------------------------------------------------------------------------
extern "C" void kernel_launch(void* const* d_in, const int* in_sizes, int n_in,
                              void* d_out, int out_size, void* d_ws, size_t ws_size,
                              hipStream_t stream) {
  const float* feat  = (const float*)d_in[0];
  const float* fcw   = (const float*)d_in[1];
  const float* attnw = (const float*)d_in[2];
  const int* src     = (const int*)d_in[3];
  const int* dst     = (const int*)d_in[4];
  float* out = (float*)d_out;

  char* ws = (char*)d_ws;
  __hip_bfloat16* z = (__hip_bfloat16*)ws;
  ws += (size_t)N_NODES * OUT_DIM * sizeof(__hip_bfloat16);  // 6.4 MB
  float* asrc = (float*)ws;   ws += (size_t)N_NODES * sizeof(float);
  float* adst = (float*)ws;   ws += (size_t)N_NODES * sizeof(float);
  int* cnt = (int*)ws;        ws += (size_t)NB * CNT_STRIDE * sizeof(int);  // 25 KB
  unsigned* pairs = (unsigned*)ws; ws += (size_t)NB * CAP_B * sizeof(unsigned);  // 4.8 MB

  hipMemsetAsync(cnt, 0, (size_t)NB * CNT_STRIDE * sizeof(int), stream);

  gat_z_bucket<<<Z_BLOCKS + EB, 256, 0, stream>>>(
      feat, fcw, attnw, z, asrc, adst, src, dst, cnt, pairs);
  gat_csr_agg<<<NB * 2, 512, 0, stream>>>(pairs, cnt, z, asrc, adst, out);
}

// Round 2
// 133.812 us; speedup vs baseline: 1.1159x; 1.1159x over previous
//
#include <hip/hip_runtime.h>
#include <hip/hip_bf16.h>
#include <hip/hip_fp16.h>

#define N_NODES 50000
#define N_EDGES 800000
#define IN_DIM 128
#define OUT_DIM 64
#define NEG_SLOPE 0.01f
#define NEG_INF (-3.0e38f)

#define N_STRIPS (N_NODES / 16)       // 3125 16-node MFMA strips
#define Z_BLOCKS ((N_STRIPS + 3) / 4) // 782 (4 waves/block, 1 strip/wave)
#define E_I4 (N_EDGES / 4)            // 200000 int4 edge groups

// bucket sort: 128 nodes/bucket; block-local count -> reserve -> place
#define NB ((N_NODES + 127) / 128)    // 391 buckets
#define CAP_B 3072                     // slab capacity (mean occupancy 2046)
#define CNT_STRIDE 16                  // 64B line per bucket cursor
#define EB 200                         // edge blocks (was 100: halve LDS-atomic serialization)
#define CHUNK_I4 (E_I4 / EB)           // 1000 int4 = 4000 edges per block

typedef __bf16 bf16x8 __attribute__((ext_vector_type(8)));
typedef float f32x4 __attribute__((ext_vector_type(4)));

__device__ __forceinline__ unsigned short f2bf_us(float f) {
  __hip_bfloat16 h = __float2bfloat16(f);  // RNE
  return *reinterpret_cast<unsigned short*>(&h);
}
__device__ __forceinline__ bf16x8 pack_bf16(float4 lo, float4 hi) {
  union { bf16x8 v; unsigned short u[8]; } r;
  r.u[0] = f2bf_us(lo.x); r.u[1] = f2bf_us(lo.y);
  r.u[2] = f2bf_us(lo.z); r.u[3] = f2bf_us(lo.w);
  r.u[4] = f2bf_us(hi.x); r.u[5] = f2bf_us(hi.y);
  r.u[6] = f2bf_us(hi.z); r.u[7] = f2bf_us(hi.w);
  return r.v;
}
__device__ __forceinline__ float bflo(unsigned u) {
  return __uint_as_float(u << 16);
}
__device__ __forceinline__ float bfhi(unsigned u) {
  return __uint_as_float(u & 0xffff0000u);
}

// ---------------------------------------------------------------------------
// Stage 1 (fused). Blocks [0, Z_BLOCKS): MFMA z-GEMM. Blocks [Z_BLOCKS,...):
// bucket pass (LDS count -> one reserve atomic per (block,bucket) -> place).
// ---------------------------------------------------------------------------
__global__ __launch_bounds__(256) void gat_z_bucket(
    const float* __restrict__ feat, const float* __restrict__ fcw,
    const float* __restrict__ attnw, __hip_bfloat16* __restrict__ z,
    float* __restrict__ asrc, float* __restrict__ adst,
    const int* __restrict__ src, const int* __restrict__ dst,
    int* __restrict__ cnt, unsigned* __restrict__ pairs) {
  if (blockIdx.x >= Z_BLOCKS) {
    __shared__ int hist[NB];
    __shared__ int curs[NB];
    const int tid = threadIdx.x;
    const int i0 = (blockIdx.x - Z_BLOCKS) * CHUNK_I4;
    for (int i = tid; i < NB; i += 256) hist[i] = 0;
    __syncthreads();
    for (int t = i0 + tid; t < i0 + CHUNK_I4; t += 256) {
      int4 d = ((const int4*)dst)[t];
      atomicAdd(&hist[d.x >> 7], 1);
      atomicAdd(&hist[d.y >> 7], 1);
      atomicAdd(&hist[d.z >> 7], 1);
      atomicAdd(&hist[d.w >> 7], 1);
    }
    __syncthreads();
    for (int i = tid; i < NB; i += 256) {
      int h = hist[i];
      curs[i] = h ? atomicAdd(cnt + i * CNT_STRIDE, h) : 0;
    }
    __syncthreads();
    for (int t = i0 + tid; t < i0 + CHUNK_I4; t += 256) {
      int4 s = ((const int4*)src)[t];
      int4 d = ((const int4*)dst)[t];
#define BKT_PUT(dd, ss)                                                    \
  {                                                                        \
    int b = (dd) >> 7;                                                     \
    int r = atomicAdd(&curs[b], 1);                                        \
    if (r < CAP_B)                                                         \
      pairs[(size_t)b * CAP_B + r] =                                       \
          ((unsigned)((dd) & 127) << 16) | (unsigned)(ss);                 \
  }
      BKT_PUT(d.x, s.x)
      BKT_PUT(d.y, s.y)
      BKT_PUT(d.z, s.z)
      BKT_PUT(d.w, s.w)
#undef BKT_PUT
    }
    return;
  }

  const int lane = threadIdx.x & 63;
  const int m = lane & 15;
  const int quad = lane >> 4;
  const int wv = blockIdx.x * 4 + (threadIdx.x >> 6);
  if (wv >= N_STRIPS) return;
  const int n0 = wv * 16;

  bf16x8 bfrag[4][4];
#pragma unroll
  for (int t = 0; t < 4; ++t) {
    const float* wr = fcw + (size_t)(m + 16 * t) * IN_DIM + quad * 8;
#pragma unroll
    for (int c = 0; c < 4; ++c) {
      float4 lo = *(const float4*)(wr + c * 32);
      float4 hi = *(const float4*)(wr + c * 32 + 4);
      bfrag[t][c] = pack_bf16(lo, hi);
    }
  }

  f32x4 acc[4] = {{0.f, 0.f, 0.f, 0.f}, {0.f, 0.f, 0.f, 0.f},
                  {0.f, 0.f, 0.f, 0.f}, {0.f, 0.f, 0.f, 0.f}};
  const float* ar = feat + (size_t)(n0 + m) * IN_DIM + quad * 8;
#pragma unroll
  for (int c = 0; c < 4; ++c) {
    float4 lo = *(const float4*)(ar + c * 32);
    float4 hi = *(const float4*)(ar + c * 32 + 4);
    const bf16x8 af = pack_bf16(lo, hi);
#pragma unroll
    for (int t = 0; t < 4; ++t)
      acc[t] = __builtin_amdgcn_mfma_f32_16x16x32_bf16(af, bfrag[t][c],
                                                       acc[t], 0, 0, 0);
  }

#pragma unroll
  for (int t = 0; t < 4; ++t)
#pragma unroll
    for (int r = 0; r < 4; ++r)
      z[(size_t)(n0 + quad * 4 + r) * OUT_DIM + m + 16 * t] =
          __float2bfloat16(acc[t][r]);

  float aws[4], awd[4];
#pragma unroll
  for (int t = 0; t < 4; ++t) {
    aws[t] = attnw[m + 16 * t];
    awd[t] = attnw[OUT_DIM + m + 16 * t];
  }
  float ps[4], pd[4];
#pragma unroll
  for (int r = 0; r < 4; ++r) {
    float s = 0.f, d = 0.f;
#pragma unroll
    for (int t = 0; t < 4; ++t) {
      s = fmaf(acc[t][r], aws[t], s);
      d = fmaf(acc[t][r], awd[t], d);
    }
    ps[r] = s;
    pd[r] = d;
  }
#pragma unroll
  for (int off = 1; off < 16; off <<= 1) {
#pragma unroll
    for (int r = 0; r < 4; ++r) {
      ps[r] += __shfl_xor(ps[r], off, 64);
      pd[r] += __shfl_xor(pd[r], off, 64);
    }
  }
  if (m == 0) {
#pragma unroll
    for (int r = 0; r < 4; ++r) {
      asrc[n0 + quad * 4 + r] = ps[r];
      adst[n0 + quad * 4 + r] = pd[r];
    }
  }
}

// ---------------------------------------------------------------------------
// Fused bucket-local CSR + aggregation, 4 nodes per wave (16 lanes/node).
// Four blocks per bucket (quarter = 32 nodes, 512 thr = 8 waves x 4 nodes).
// Chunk = 16 edges == mean degree, so per-chunk softmax overhead (max-reduce,
// rescale, pack) and the final butterfly are amortized across 4 nodes per
// wave instruction; 4x memory-level parallelism per gather instruction.
// Lane roles within a 16-lane group: sl = edge-idx (softmax phase);
// (eg = sl>>2, j2 = sl&3) = (edge subgroup, 16-col quarter) in gather phase.
// ---------------------------------------------------------------------------
__global__ __launch_bounds__(512) void gat_csr_agg(
    const unsigned* __restrict__ pairs, const int* __restrict__ cnt,
    const __hip_bfloat16* __restrict__ zb, const float* __restrict__ asrc,
    const float* __restrict__ adst, float* __restrict__ out) {
  __shared__ int hist[32];
  __shared__ int noff[33];
  __shared__ int cur[32];
  __shared__ int lsrc[CAP_B];
  const int tid = threadIdx.x;
  const int b = blockIdx.x >> 2;
  const int q = blockIdx.x & 3;
  const int c = min(cnt[b * CNT_STRIDE], CAP_B);
  const unsigned* __restrict__ bp = pairs + (size_t)b * CAP_B;

  if (tid < 32) hist[tid] = 0;
  __syncthreads();
  for (int i = tid; i < c; i += 512) {
    const int ln = (int)(bp[i] >> 16);
    if ((ln >> 5) == q) atomicAdd(&hist[ln & 31], 1);
  }
  __syncthreads();
  if (tid < 32) {
    const int h = hist[tid];
    int s = h;
#pragma unroll
    for (int off = 1; off < 32; off <<= 1) {
      const int u = __shfl_up(s, off, 64);
      if (tid >= off) s += u;
    }
    noff[tid] = s - h;
    cur[tid] = s - h;
    if (tid == 31) noff[32] = s;
  }
  __syncthreads();
  for (int i = tid; i < c; i += 512) {
    const unsigned p = bp[i];
    const int ln = (int)(p >> 16);
    if ((ln >> 5) == q) {
      const int r = atomicAdd(&cur[ln & 31], 1);
      lsrc[r] = (int)(p & 0xFFFFu);
    }
  }
  __syncthreads();

  const int lane = tid & 63;
  const int wv = tid >> 6;      // wave 0..7
  const int g = lane >> 4;      // group in wave 0..3
  const int sl = lane & 15;     // sublane in group
  const int j2 = sl & 3;        // col quarter: cols 16*j2 .. 16*j2+15
  const int eg = sl >> 2;       // edge subgroup 0..3
  const int gbase = lane & 48;  // group's base lane

  const int ln = wv * 4 + g;    // local node 0..31
  const int node = b * 128 + q * 32 + ln;
  if (node >= N_NODES) return;

  const uint4* __restrict__ zp4 = (const uint4*)zb;  // 8 uint4 per 64-col row
  const int o0 = noff[ln];
  const int o1 = noff[ln + 1];
  float4* __restrict__ orow = (float4*)(out + (size_t)node * OUT_DIM);
  if (o0 == o1) {  // no incoming edges: elu(0/1) = 0
    if (sl < 4) {
      const float4 zv = {0.f, 0.f, 0.f, 0.f};
#pragma unroll
      for (int v = 0; v < 4; ++v) orow[4 * sl + v] = zv;
    }
    return;
  }
  const float ad = adst[node];

  float m = NEG_INF, dsum = 0.f;
  float acc[16];
#pragma unroll
  for (int cc = 0; cc < 16; ++cc) acc[cc] = 0.f;

  for (int base = o0; base < o1; base += 16) {
    const int cnt2 = min(16, o1 - base);
    int s = 0;
    float ev = NEG_INF;
    if (sl < cnt2) {
      s = lsrc[base + sl];
      const float v = asrc[s] + ad;
      ev = v > 0.f ? v : NEG_SLOPE * v;
    }
    float cm = ev;
#pragma unroll
    for (int off = 1; off < 16; off <<= 1)
      cm = fmaxf(cm, __shfl_xor(cm, off, 64));
    const float nm = fmaxf(m, cm);
    const float scale = __expf(m - nm);  // first chunk: exp(-inf) = 0
    dsum *= scale;
#pragma unroll
    for (int cc = 0; cc < 16; ++cc) acc[cc] *= scale;
    m = nm;

    const float w = (sl < cnt2) ? __expf(ev - m) : 0.f;  // 0 beyond cnt
    dsum += w;
    // pack s (16b) | f16(w) (16b); s=0,w=0 for idle lanes -> harmless
    const unsigned pk =
        (unsigned)s |
        ((unsigned)__half_as_ushort(__float2half(w)) << 16);

    const int ngr = (cnt2 + 3) >> 2;
    for (int gg = 0; gg < ngr; ++gg) {
      const unsigned pa = __shfl(pk, gbase + 4 * gg + eg, 64);
      const int sa = (int)(pa & 0xFFFFu);
      const float wa =
          __half2float(__ushort_as_half((unsigned short)(pa >> 16)));
      const uint4 ua = zp4[(size_t)sa * 8 + 2 * j2];
      const uint4 ub = zp4[(size_t)sa * 8 + 2 * j2 + 1];
      acc[0] = fmaf(wa, bflo(ua.x), acc[0]);
      acc[1] = fmaf(wa, bfhi(ua.x), acc[1]);
      acc[2] = fmaf(wa, bflo(ua.y), acc[2]);
      acc[3] = fmaf(wa, bfhi(ua.y), acc[3]);
      acc[4] = fmaf(wa, bflo(ua.z), acc[4]);
      acc[5] = fmaf(wa, bfhi(ua.z), acc[5]);
      acc[6] = fmaf(wa, bflo(ua.w), acc[6]);
      acc[7] = fmaf(wa, bfhi(ua.w), acc[7]);
      acc[8] = fmaf(wa, bflo(ub.x), acc[8]);
      acc[9] = fmaf(wa, bfhi(ub.x), acc[9]);
      acc[10] = fmaf(wa, bflo(ub.y), acc[10]);
      acc[11] = fmaf(wa, bfhi(ub.y), acc[11]);
      acc[12] = fmaf(wa, bflo(ub.z), acc[12]);
      acc[13] = fmaf(wa, bfhi(ub.z), acc[13]);
      acc[14] = fmaf(wa, bflo(ub.w), acc[14]);
      acc[15] = fmaf(wa, bfhi(ub.w), acc[15]);
    }
  }

  // reduce across the 4 edge subgroups (lanes sl, sl^4, sl^8 share j2)
#pragma unroll
  for (int off = 4; off <= 8; off <<= 1)
#pragma unroll
    for (int cc = 0; cc < 16; ++cc) acc[cc] += __shfl_xor(acc[cc], off, 64);
#pragma unroll
  for (int off = 1; off < 16; off <<= 1) dsum += __shfl_xor(dsum, off, 64);

  if (eg == 0) {  // sl == j2 < 4
    const float inv = 1.f / (dsum > 0.f ? dsum : 1.f);
#pragma unroll
    for (int v = 0; v < 4; ++v) {
      float4 r;
      float h;
      h = acc[4 * v + 0] * inv; r.x = h > 0.f ? h : expm1f(h);
      h = acc[4 * v + 1] * inv; r.y = h > 0.f ? h : expm1f(h);
      h = acc[4 * v + 2] * inv; r.z = h > 0.f ? h : expm1f(h);
      h = acc[4 * v + 3] * inv; r.w = h > 0.f ? h : expm1f(h);
      orow[4 * j2 + v] = r;
    }
  }
}

// ---------------------------------------------------------------------------
extern "C" void kernel_launch(void* const* d_in, const int* in_sizes, int n_in,
                              void* d_out, int out_size, void* d_ws, size_t ws_size,
                              hipStream_t stream) {
  const float* feat  = (const float*)d_in[0];
  const float* fcw   = (const float*)d_in[1];
  const float* attnw = (const float*)d_in[2];
  const int* src     = (const int*)d_in[3];
  const int* dst     = (const int*)d_in[4];
  float* out = (float*)d_out;

  char* ws = (char*)d_ws;
  __hip_bfloat16* z = (__hip_bfloat16*)ws;
  ws += (size_t)N_NODES * OUT_DIM * sizeof(__hip_bfloat16);  // 6.4 MB
  float* asrc = (float*)ws;   ws += (size_t)N_NODES * sizeof(float);
  float* adst = (float*)ws;   ws += (size_t)N_NODES * sizeof(float);
  int* cnt = (int*)ws;        ws += (size_t)NB * CNT_STRIDE * sizeof(int);  // 25 KB
  unsigned* pairs = (unsigned*)ws; ws += (size_t)NB * CAP_B * sizeof(unsigned);  // 4.8 MB

  hipMemsetAsync(cnt, 0, (size_t)NB * CNT_STRIDE * sizeof(int), stream);

  gat_z_bucket<<<Z_BLOCKS + EB, 256, 0, stream>>>(
      feat, fcw, attnw, z, asrc, adst, src, dst, cnt, pairs);
  gat_csr_agg<<<NB * 4, 512, 0, stream>>>(pairs, cnt, z, asrc, adst, out);
}